// Round 1
// baseline (43.765 us; speedup 1.0000x reference)
//
#include <hip/hip_runtime.h>
#include <math.h>

#define VOCAB   100
#define T_STEPS 128
#define BATCH   1024
#define M_SLOTS 32
#define DQ      64
#define DV      64

// d_ws layout (floats): att[VOCAB*M_SLOTS] | sq[VOCAB] (incl. bf) | sv[VOCAB]

__global__ __launch_bounds__(64) void prep_tables(
    const float* __restrict__ Eq,
    const float* __restrict__ Ev,
    const float* __restrict__ Wa,
    const float* __restrict__ ba,
    const float* __restrict__ Wf,
    const float* __restrict__ bf,
    float* __restrict__ ws) {
  const int q = blockIdx.x;    // vocab id 0..99
  const int d = threadIdx.x;   // 0..63
  __shared__ float eq_lds[DQ];

  float e  = Eq[q * DQ + d];
  eq_lds[d] = e;
  float sq = e * Wf[d];                    // Eq[q] . Wf_q
  float sv = Ev[q * DV + d] * Wf[DQ + d];  // Ev[q] . Wf_r
  #pragma unroll
  for (int k = 32; k >= 1; k >>= 1) {
    sq += __shfl_xor(sq, k);
    sv += __shfl_xor(sv, k);
  }
  if (d == 0) {
    ws[VOCAB * M_SLOTS + q]         = sq + bf[0];
    ws[VOCAB * M_SLOTS + VOCAB + q] = sv;
  }
  __syncthreads();

  // logits -> softmax for m = d (first 32 lanes only)
  float l = -INFINITY;
  if (d < M_SLOTS) {
    l = ba[d];
    for (int k = 0; k < DQ; ++k) l = fmaf(eq_lds[k], Wa[k * M_SLOTS + d], l);
  }
  // butterfly within each 32-lane half (masks <= 16 never cross halves;
  // upper half holds -inf/NaN junk and never stores)
  float mx = l;
  #pragma unroll
  for (int k = 16; k >= 1; k >>= 1) mx = fmaxf(mx, __shfl_xor(mx, k));
  float ex = expf(l - mx);
  float s = ex;
  #pragma unroll
  for (int k = 16; k >= 1; k >>= 1) s += __shfl_xor(s, k);
  if (d < M_SLOTS) ws[q * M_SLOTS + d] = ex / s;
}

#define BPB     4              // batches per block (one 32-lane group each)
#define THREADS (BPB * 32)     // 128 threads = 2 waves

__global__ __launch_bounds__(THREADS) void dkvmn_scan(
    const int* __restrict__ questions,
    const int* __restrict__ answers,
    const float* __restrict__ ws,
    float* __restrict__ out) {
  __shared__ float att_lds[VOCAB * M_SLOTS];
  __shared__ int   q_lds[T_STEPS * BPB];
  __shared__ float sval_lds[T_STEPS * BPB];
  __shared__ float base_lds[T_STEPS * BPB];

  const int tid = threadIdx.x;
  const int b0  = blockIdx.x * BPB;

  // stage A: attention table -> LDS ([q][m], stride 32; read bank = m later)
  for (int i = tid; i < VOCAB * M_SLOTS; i += THREADS) att_lds[i] = ws[i];

  const float* sq_g = ws + VOCAB * M_SLOTS;
  const float* sv_g = ws + VOCAB * M_SLOTS + VOCAB;

  // stage B: per-(t, local-batch) scalars -> LDS
  for (int p = tid; p < T_STEPS * BPB; p += THREADS) {
    int t = p >> 2, j = p & (BPB - 1);
    int gi = t * BATCH + b0 + j;
    int q = questions[gi];
    int a = answers[gi];
    int w = (q * 2 + a) % VOCAB;
    q_lds[p]    = q;
    sval_lds[p] = sv_g[w];
    base_lds[p] = sq_g[q];
  }
  __syncthreads();

  const int g = tid >> 5;    // local batch 0..3
  const int m = tid & 31;    // memory slot
  const int b = b0 + g;

  float rvec = 0.f;          // lane-held slice of the collapsed memory state

  #pragma unroll 8
  for (int t = 0; t < T_STEPS; ++t) {
    const int p = t * BPB + g;
    const int q = q_lds[p];
    const float sval = sval_lds[p];
    const float av = att_lds[q * M_SLOTS + m];   // bank m: conflict-free

    // prediction: dot(att_row, rvec) — off the loop-carried path
    float sum = av * rvec;
    sum += __shfl_xor(sum, 16);
    sum += __shfl_xor(sum, 8);
    sum += __shfl_xor(sum, 4);
    sum += __shfl_xor(sum, 2);
    sum += __shfl_xor(sum, 1);
    if (m == 0) out[t * BATCH + b] = base_lds[p] + sum;

    // state update (exclusive: after pred)
    rvec = fmaf(av, sval, rvec);
  }
}

extern "C" void kernel_launch(void* const* d_in, const int* in_sizes, int n_in,
                              void* d_out, int out_size, void* d_ws, size_t ws_size,
                              hipStream_t stream) {
  const int*   questions = (const int*)d_in[0];
  const int*   answers   = (const int*)d_in[1];
  const float* Eq = (const float*)d_in[2];
  const float* Ev = (const float*)d_in[3];
  const float* Wa = (const float*)d_in[4];
  const float* ba = (const float*)d_in[5];
  const float* Wf = (const float*)d_in[6];
  const float* bf = (const float*)d_in[7];

  float* ws  = (float*)d_ws;
  float* out = (float*)d_out;

  hipLaunchKernelGGL(prep_tables, dim3(VOCAB), dim3(64), 0, stream,
                     Eq, Ev, Wa, ba, Wf, bf, ws);
  hipLaunchKernelGGL(dkvmn_scan, dim3(BATCH / BPB), dim3(THREADS), 0, stream,
                     questions, answers, ws, out);
}

// Round 2
// 31.064 us; speedup vs baseline: 1.4089x; 1.4089x over previous
//
#include <hip/hip_runtime.h>
#include <math.h>

#define VOCAB   100
#define T_STEPS 128
#define BATCH   1024
#define M_SLOTS 32
#define DQ      64
#define DV      64

// ws layout (floats): K[100*101] (row stride 101, padded) | sq[100] (incl bf) | sv[100]
#define WS_K    0
#define WS_SQ   10100
#define WS_SV   10200

// ---------------------------------------------------------------------------
// prep: one block, 1024 threads. Computes:
//   att[p][m] = softmax_m(Eq[p].Wa + ba)   (kept in LDS, transposed [m][p])
//   K[q][p]   = dot_m(att[q], att[p])      -> ws (stride 101)
//   sq[v]     = Eq[v].Wf_q + bf            -> ws
//   sv[v]     = Ev[v].Wf_r                 -> ws
// ---------------------------------------------------------------------------
__global__ __launch_bounds__(1024) void prep(
    const float* __restrict__ Eq,
    const float* __restrict__ Ev,
    const float* __restrict__ Wa,
    const float* __restrict__ ba,
    const float* __restrict__ Wf,
    const float* __restrict__ bf,
    float* __restrict__ ws) {
  __shared__ float atT[M_SLOTS * VOCAB];   // [m][p] : read conflict-free by K phase

  const int tid = threadIdx.x;
  const int m   = tid & 31;     // memory slot
  const int g   = tid >> 5;     // 0..31 : p-group

  // ---- logits for p in {g, g+32, g+64, g+96} ----
  const int p0 = g, p1 = g + 32, p2 = g + 64, p3 = g + 96;
  const int p3c = (p3 < VOCAB) ? p3 : 0;   // clamp for safe loads
  const float4* Eq4 = (const float4*)Eq;

  float acc0 = 0.f, acc1 = 0.f, acc2 = 0.f, acc3 = 0.f;
  #pragma unroll
  for (int kk = 0; kk < DQ / 4; ++kk) {
    const int k = kk * 4;
    float4 e0 = Eq4[p0 * 16 + kk];
    float4 e1 = Eq4[p1 * 16 + kk];
    float4 e2 = Eq4[p2 * 16 + kk];
    float4 e3 = Eq4[p3c * 16 + kk];
    float w0 = Wa[(k + 0) * M_SLOTS + m];
    float w1 = Wa[(k + 1) * M_SLOTS + m];
    float w2 = Wa[(k + 2) * M_SLOTS + m];
    float w3 = Wa[(k + 3) * M_SLOTS + m];
    acc0 = fmaf(e0.x, w0, fmaf(e0.y, w1, fmaf(e0.z, w2, fmaf(e0.w, w3, acc0))));
    acc1 = fmaf(e1.x, w0, fmaf(e1.y, w1, fmaf(e1.z, w2, fmaf(e1.w, w3, acc1))));
    acc2 = fmaf(e2.x, w0, fmaf(e2.y, w1, fmaf(e2.z, w2, fmaf(e2.w, w3, acc2))));
    acc3 = fmaf(e3.x, w0, fmaf(e3.y, w1, fmaf(e3.z, w2, fmaf(e3.w, w3, acc3))));
  }
  const float bam = ba[m];
  acc0 += bam; acc1 += bam; acc2 += bam; acc3 += bam;

  // ---- softmax over m (32-lane groups; masks <=16 stay in-group) ----
  float l[4] = {acc0, acc1, acc2, acc3};
  int   pp[4] = {p0, p1, p2, p3};
  #pragma unroll
  for (int sl = 0; sl < 4; ++sl) {
    float mx = l[sl];
    #pragma unroll
    for (int k = 16; k >= 1; k >>= 1) mx = fmaxf(mx, __shfl_xor(mx, k));
    float ex = __expf(l[sl] - mx);
    float sm = ex;
    #pragma unroll
    for (int k = 16; k >= 1; k >>= 1) sm += __shfl_xor(sm, k);
    if (pp[sl] < VOCAB) atT[m * VOCAB + pp[sl]] = ex / sm;
  }
  __syncthreads();

  // ---- K phase: wave w handles rows Q = w, w+16, ... ----
  const int wave = tid >> 6;
  const int lane = tid & 63;
  for (int Q = wave; Q < VOCAB; Q += 16) {
    #pragma unroll
    for (int half = 0; half < 2; ++half) {
      const int p = half * 64 + lane;
      if (p < VOCAB) {
        float a = 0.f;
        #pragma unroll
        for (int mm = 0; mm < M_SLOTS; ++mm)
          a = fmaf(atT[mm * VOCAB + Q], atT[mm * VOCAB + p], a);  // broadcast * c-free
        ws[WS_K + Q * (VOCAB + 1) + p] = a;
      }
    }
  }

  // ---- sq / sv scalar tables ----
  const float4* Wf4 = (const float4*)Wf;
  if (tid < VOCAB) {
    float s = 0.f;
    #pragma unroll
    for (int kk = 0; kk < DQ / 4; ++kk) {
      float4 e = Eq4[tid * 16 + kk];
      float4 w = Wf4[kk];
      s = fmaf(e.x, w.x, fmaf(e.y, w.y, fmaf(e.z, w.z, fmaf(e.w, w.w, s))));
    }
    ws[WS_SQ + tid] = s + bf[0];
  } else if (tid >= 128 && tid < 128 + VOCAB) {
    const int v = tid - 128;
    const float4* Ev4 = (const float4*)Ev;
    float s = 0.f;
    #pragma unroll
    for (int kk = 0; kk < DV / 4; ++kk) {
      float4 e = Ev4[v * 16 + kk];
      float4 w = Wf4[16 + kk];   // Wf_r half
      s = fmaf(e.x, w.x, fmaf(e.y, w.y, fmaf(e.z, w.z, fmaf(e.w, w.w, s))));
    }
    ws[WS_SV + v] = s;
  }
}

// ---------------------------------------------------------------------------
// main: pred[t,b] = sq[q_tb] + sum_{s<t} sv[w_sb] * K[q_tb][q_sb]
// Block = TB batches x 128 t (256 threads). Lanes within a wave share the
// batch -> s-scan reads are wave-uniform broadcasts; only Krow[q_s] is a
// gather (row stride 101 -> banks spread, ~2-3 way avg).
// ---------------------------------------------------------------------------
#define TB      2
#define THREADS (TB * T_STEPS)

__global__ __launch_bounds__(THREADS) void qform(
    const int* __restrict__ questions,
    const int* __restrict__ answers,
    const float* __restrict__ ws,
    float* __restrict__ out) {
  __shared__ float K_lds[VOCAB * (VOCAB + 1)];        // 10100 floats
  __shared__ __align__(16) float2 sb[TB * T_STEPS];   // {sval_s, q_s bits}

  const int tid = threadIdx.x;
  const int b0  = blockIdx.x * TB;

  // stage K (issue these global loads first; they dominate)
  const float4* Kg4 = (const float4*)(ws + WS_K);
  float4* Kl4 = (float4*)K_lds;
  #pragma unroll
  for (int it = 0; it < 10; ++it) {
    const int i = tid + it * THREADS;
    if (i < (VOCAB * (VOCAB + 1)) / 4) Kl4[i] = Kg4[i];
  }

  // stage per-(t, local-batch) scalars
  {
    const int j  = tid >> 7;
    const int t  = tid & 127;
    const int gi = t * BATCH + b0 + j;
    const int q  = questions[gi];
    const int a  = answers[gi];
    const int w  = (q * 2 + a) % VOCAB;
    sb[j * T_STEPS + t] = make_float2(ws[WS_SV + w], __int_as_float(q));
  }
  __syncthreads();

  const int j = tid >> 7;          // local batch (wave-uniform)
  const int t = tid & 127;
  const int myq = __float_as_int(sb[j * T_STEPS + t].y);
  const float* Krow = K_lds + myq * (VOCAB + 1);
  const float2* sbj = sb + j * T_STEPS;

  float a0 = 0.f, a1 = 0.f;
  int s = 0;
  for (; s + 2 <= t; s += 2) {
    float4 x = *(const float4*)(sbj + s);   // wave-uniform b128 broadcast
    a0 = fmaf(x.x, Krow[__float_as_int(x.y)], a0);
    a1 = fmaf(x.z, Krow[__float_as_int(x.w)], a1);
  }
  float acc = a0 + a1;
  if (s < t) {
    float2 x = sbj[s];
    acc = fmaf(x.x, Krow[__float_as_int(x.y)], acc);
  }
  out[t * BATCH + b0 + j] = acc + ws[WS_SQ + myq];
}

extern "C" void kernel_launch(void* const* d_in, const int* in_sizes, int n_in,
                              void* d_out, int out_size, void* d_ws, size_t ws_size,
                              hipStream_t stream) {
  const int*   questions = (const int*)d_in[0];
  const int*   answers   = (const int*)d_in[1];
  const float* Eq = (const float*)d_in[2];
  const float* Ev = (const float*)d_in[3];
  const float* Wa = (const float*)d_in[4];
  const float* ba = (const float*)d_in[5];
  const float* Wf = (const float*)d_in[6];
  const float* bf = (const float*)d_in[7];

  float* ws  = (float*)d_ws;
  float* out = (float*)d_out;

  hipLaunchKernelGGL(prep, dim3(1), dim3(1024), 0, stream,
                     Eq, Ev, Wa, ba, Wf, bf, ws);
  hipLaunchKernelGGL(qform, dim3(BATCH / TB), dim3(THREADS), 0, stream,
                     questions, answers, ws, out);
}

// Round 3
// 20.750 us; speedup vs baseline: 2.1092x; 1.4971x over previous
//
#include <hip/hip_runtime.h>
#include <math.h>

#define VOCAB 100
#define TT    128
#define BB    1024
#define MM    32
#define DQ    64
#define DV    64
#define BPB   8                 // batches per block
#define NTHR  256               // 8 groups x 32 lanes
#define CH    32                // t-chunk for pacc
#define NCH   (TT / CH)

// Single fused kernel: every block builds the tables itself (Eq/Wa/Ev/Wf are
// tiny and L2-resident), then scans BPB batches. Prediction reduction is
// deferred: per step each lane m writes av*rvec to pacc[t][m] (padded, bank
// conflict-free), then lane m reduces row t=m per chunk. Loop-carried dep is
// one fmaf per step.
__global__ __launch_bounds__(NTHR) void dkvmn_fused(
    const int* __restrict__ questions,
    const int* __restrict__ answers,
    const float* __restrict__ Eq,
    const float* __restrict__ Ev,
    const float* __restrict__ Wa,
    const float* __restrict__ ba,
    const float* __restrict__ Wf,
    const float* __restrict__ bf,
    float* __restrict__ out) {

  __shared__ float att_l[VOCAB * MM];                 // [q][m] -> bank m
  __shared__ float sq_l[VOCAB];
  __shared__ float sv_l[VOCAB];
  __shared__ __align__(16) float wf_l[2 * DQ + 1];    // Wf_q | Wf_r | bf
  __shared__ float2 qsv_l[BPB * TT];                  // {q bits, w bits -> sval}
  __shared__ float pred_l[TT * 9 + 8];                // [t][b_loc] stride 9
  __shared__ __align__(16) float big[BPB * CH * 33];  // pacc; head reused for Eq stage

  const int tid = threadIdx.x;
  const int b0  = blockIdx.x * BPB;
  const int g   = tid >> 5;     // local batch / group
  const int m   = tid & 31;     // memory slot

  // ---- stage Eq into big[0..6399] ----
  {
    const float4* Eq4 = (const float4*)Eq;
    float4* dst = (float4*)big;
    #pragma unroll
    for (int it = 0; it < 7; ++it) {
      int i = tid + it * NTHR;
      if (i < VOCAB * DQ / 4) dst[i] = Eq4[i];
    }
  }
  if (tid < 2 * DQ) wf_l[tid] = Wf[tid];
  if (tid == NTHR - 1) wf_l[2 * DQ] = bf[0];

  // ---- load q/a; store q and write-index w (converted to sval later) ----
  #pragma unroll
  for (int it = 0; it < 4; ++it) {
    int idx = tid + it * NTHR;          // < 1024 = TT*BPB
    int t = idx >> 3, j = idx & 7;
    int gi = t * BB + b0 + j;
    int q = questions[gi];
    int a = answers[gi];
    int w = (q * 2 + a) % VOCAB;
    qsv_l[j * TT + t] = make_float2(__int_as_float(q), __int_as_float(w));
  }

  // ---- Wa column for my slot m (redundant across groups; L2-hot) ----
  float wa[DQ];
  #pragma unroll
  for (int k = 0; k < DQ; ++k) wa[k] = Wa[k * MM + m];
  const float bam = ba[m];

  __syncthreads();

  // ---- att rows q = g, g+8, ... (softmax across the 32-lane group) ----
  for (int q = g; q < VOCAB; q += BPB) {
    const float4* eq4 = (const float4*)(big + q * DQ);
    float ax = 0.f, ay = 0.f, az = 0.f, aw = 0.f;
    #pragma unroll
    for (int k4 = 0; k4 < DQ / 4; ++k4) {
      float4 e = eq4[k4];
      ax = fmaf(e.x, wa[k4 * 4 + 0], ax);
      ay = fmaf(e.y, wa[k4 * 4 + 1], ay);
      az = fmaf(e.z, wa[k4 * 4 + 2], az);
      aw = fmaf(e.w, wa[k4 * 4 + 3], aw);
    }
    float l = (ax + ay) + (az + aw) + bam;
    float mx = l;
    #pragma unroll
    for (int k = 16; k >= 1; k >>= 1) mx = fmaxf(mx, __shfl_xor(mx, k));
    float ex = __expf(l - mx);
    float sm = ex;
    #pragma unroll
    for (int k = 16; k >= 1; k >>= 1) sm += __shfl_xor(sm, k);
    att_l[q * MM + m] = ex * __builtin_amdgcn_rcpf(sm);
  }

  // ---- sq[v] = Eq[v].Wf_q + bf ; sv[v] = Ev[v].Wf_r ----
  if (tid < VOCAB) {
    const float4* eq4 = (const float4*)(big + tid * DQ);
    const float4* wfq = (const float4*)wf_l;
    float s = 0.f;
    #pragma unroll
    for (int k4 = 0; k4 < DQ / 4; ++k4) {
      float4 e = eq4[k4], w = wfq[k4];
      s = fmaf(e.x, w.x, fmaf(e.y, w.y, fmaf(e.z, w.z, fmaf(e.w, w.w, s))));
    }
    sq_l[tid] = s + wf_l[2 * DQ];
  } else if (tid >= 128 && tid < 128 + VOCAB) {
    int v = tid - 128;
    const float4* ev4 = (const float4*)Ev + v * (DV / 4);
    const float4* wfr = (const float4*)(wf_l + DQ);
    float s = 0.f;
    #pragma unroll
    for (int k4 = 0; k4 < DV / 4; ++k4) {
      float4 e = ev4[k4], w = wfr[k4];
      s = fmaf(e.x, w.x, fmaf(e.y, w.y, fmaf(e.z, w.z, fmaf(e.w, w.w, s))));
    }
    sv_l[v] = s;
  }

  __syncthreads();

  // ---- convert stored w -> sval (each element owned by one thread) ----
  #pragma unroll
  for (int it = 0; it < 4; ++it) {
    int idx = tid + it * NTHR;
    int t = idx >> 3, j = idx & 7;
    float2 x = qsv_l[j * TT + t];
    x.y = sv_l[__float_as_int(x.y)];
    qsv_l[j * TT + t] = x;
  }
  __syncthreads();   // also: last Eq use done; big becomes pacc

  // ---- scan: rvec[m] carried in-register; pred partials deferred to LDS ----
  float rvec = 0.f;
  const float2* qsv_g = qsv_l + g * TT;
  float* pacc_g = big + g * (CH * 33);

  for (int c = 0; c < NCH; ++c) {
    #pragma unroll 8
    for (int t2 = 0; t2 < CH; ++t2) {
      float2 x = qsv_g[c * CH + t2];            // b64 broadcast
      int q = __float_as_int(x.x);
      float av = att_l[q * MM + m];             // bank m, 2-way = free
      pacc_g[t2 * 33 + m] = av * rvec;          // banks (t2+m)%32: c-free
      rvec = fmaf(av, x.y, rvec);               // the only loop-carried dep
    }
    __syncthreads();
    {
      // lane m reduces row t_loc = m : banks (m+k)%32, conflict-free
      const float* row = pacc_g + m * 33;
      float s = 0.f;
      #pragma unroll
      for (int k = 0; k < MM; ++k) s += row[k];
      int t = c * CH + m;
      int q = __float_as_int(qsv_g[t].x);
      pred_l[t * 9 + g] = s + sq_l[q];
    }
    __syncthreads();
  }

  // ---- coalesced store: thread -> (t, half), 16B per store ----
  {
    int t = tid >> 1, h = tid & 1;
    float4 v;
    v.x = pred_l[t * 9 + h * 4 + 0];
    v.y = pred_l[t * 9 + h * 4 + 1];
    v.z = pred_l[t * 9 + h * 4 + 2];
    v.w = pred_l[t * 9 + h * 4 + 3];
    *(float4*)(out + t * BB + b0 + h * 4) = v;
  }
}

extern "C" void kernel_launch(void* const* d_in, const int* in_sizes, int n_in,
                              void* d_out, int out_size, void* d_ws, size_t ws_size,
                              hipStream_t stream) {
  const int*   questions = (const int*)d_in[0];
  const int*   answers   = (const int*)d_in[1];
  const float* Eq = (const float*)d_in[2];
  const float* Ev = (const float*)d_in[3];
  const float* Wa = (const float*)d_in[4];
  const float* ba = (const float*)d_in[5];
  const float* Wf = (const float*)d_in[6];
  const float* bf = (const float*)d_in[7];
  float* out = (float*)d_out;

  hipLaunchKernelGGL(dkvmn_fused, dim3(BB / BPB), dim3(NTHR), 0, stream,
                     questions, answers, Eq, Ev, Wa, ba, Wf, bf, out);
}

// Round 4
// 20.106 us; speedup vs baseline: 2.1767x; 1.0320x over previous
//
#include <hip/hip_runtime.h>
#include <math.h>

#define VOCAB 100
#define TT    128
#define BB    1024
#define MM    32
#define DQ    64
#define DV    64
#define BPB   8                 // batches per block (one 32-lane group each)
#define NTHR  256               // 8 groups x 32 lanes = 4 waves
#define CH    32                // t-chunk
#define NCH   (TT / CH)
#define PSTR  34                // pacc row stride: banks (2m+t2)%32, <=2-way = free

// Single fused kernel. Tables built redundantly per block (inputs are tiny,
// L2-resident). Scan phase has ZERO barriers: pacc is group-private and a
// group is half a wave, so writer==reader wave and intra-wave lgkmcnt
// ordering (compiler-inserted) is sufficient.
__global__ __launch_bounds__(NTHR) void dkvmn_fused(
    const int* __restrict__ questions,
    const int* __restrict__ answers,
    const float* __restrict__ Eq,
    const float* __restrict__ Ev,
    const float* __restrict__ Wa,
    const float* __restrict__ ba,
    const float* __restrict__ Wf,
    const float* __restrict__ bf,
    float* __restrict__ out) {

  __shared__ float att_l[VOCAB * MM];                  // [q][m] -> bank m
  __shared__ float sq_l[VOCAB];
  __shared__ float sv_l[VOCAB];
  __shared__ __align__(16) float wf_l[2 * DQ + 1];     // Wf_q | Wf_r | bf
  __shared__ __align__(16) float2 qsv_l[BPB * TT];     // {q bits, w bits -> sval}
  __shared__ float pred_l[TT * 9 + 8];                 // [t][b_loc], stride 9
  __shared__ __align__(16) float big[BPB * MM * PSTR]; // pacc (8704f); Eq stage (6400f)

  const int tid = threadIdx.x;
  const int b0  = blockIdx.x * BPB;
  const int g   = tid >> 5;     // local batch / group
  const int m   = tid & 31;     // memory slot

  // ---- stage Eq into big ----
  {
    const float4* Eq4 = (const float4*)Eq;
    float4* dst = (float4*)big;
    #pragma unroll
    for (int it = 0; it < 7; ++it) {
      int i = tid + it * NTHR;
      if (i < VOCAB * DQ / 4) dst[i] = Eq4[i];
    }
  }
  if (tid < 2 * DQ) wf_l[tid] = Wf[tid];
  if (tid == NTHR - 1) wf_l[2 * DQ] = bf[0];

  // ---- load q/a; store q and write-index w (w -> sval later) ----
  #pragma unroll
  for (int it = 0; it < 4; ++it) {
    int idx = tid + it * NTHR;          // < 1024 = TT*BPB
    int t = idx >> 3, j = idx & 7;
    int gi = t * BB + b0 + j;
    int q = questions[gi];
    int a = answers[gi];
    int w = (q * 2 + a) % VOCAB;
    qsv_l[j * TT + t] = make_float2(__int_as_float(q), __int_as_float(w));
  }

  // ---- Wa column for slot m (coalesced 128B/line, L2-hot) ----
  float wa[DQ];
  #pragma unroll
  for (int k = 0; k < DQ; ++k) wa[k] = Wa[k * MM + m];
  const float bam = ba[m];

  __syncthreads();   // (1) staging done

  // ---- att rows q = g, g+8, ... ----
  for (int q = g; q < VOCAB; q += BPB) {
    const float4* eq4 = (const float4*)(big + q * DQ);
    float ax = 0.f, ay = 0.f, az = 0.f, aw = 0.f;
    #pragma unroll
    for (int k4 = 0; k4 < DQ / 4; ++k4) {
      float4 e = eq4[k4];
      ax = fmaf(e.x, wa[k4 * 4 + 0], ax);
      ay = fmaf(e.y, wa[k4 * 4 + 1], ay);
      az = fmaf(e.z, wa[k4 * 4 + 2], az);
      aw = fmaf(e.w, wa[k4 * 4 + 3], aw);
    }
    float l = (ax + ay) + (az + aw) + bam;
    float mx = l;
    #pragma unroll
    for (int k = 16; k >= 1; k >>= 1) mx = fmaxf(mx, __shfl_xor(mx, k));
    float ex = __expf(l - mx);
    float sm = ex;
    #pragma unroll
    for (int k = 16; k >= 1; k >>= 1) sm += __shfl_xor(sm, k);
    att_l[q * MM + m] = ex * __builtin_amdgcn_rcpf(sm);
  }

  // ---- sq[v] = Eq[v].Wf_q + bf ; sv[v] = Ev[v].Wf_r ----
  if (tid < VOCAB) {
    const float4* eq4 = (const float4*)(big + tid * DQ);
    const float4* wfq = (const float4*)wf_l;
    float s = 0.f;
    #pragma unroll
    for (int k4 = 0; k4 < DQ / 4; ++k4) {
      float4 e = eq4[k4], w = wfq[k4];
      s = fmaf(e.x, w.x, fmaf(e.y, w.y, fmaf(e.z, w.z, fmaf(e.w, w.w, s))));
    }
    sq_l[tid] = s + wf_l[2 * DQ];
  } else if (tid >= 128 && tid < 128 + VOCAB) {
    int v = tid - 128;
    const float4* ev4 = (const float4*)Ev + v * (DV / 4);
    const float4* wfr = (const float4*)(wf_l + DQ);
    float s = 0.f;
    #pragma unroll
    for (int k4 = 0; k4 < DV / 4; ++k4) {
      float4 e = ev4[k4], w = wfr[k4];
      s = fmaf(e.x, w.x, fmaf(e.y, w.y, fmaf(e.z, w.z, fmaf(e.w, w.w, s))));
    }
    sv_l[v] = s;
  }

  __syncthreads();   // (2) sv_l ready

  // ---- convert stored w -> sval ----
  #pragma unroll
  for (int it = 0; it < 4; ++it) {
    int idx = tid + it * NTHR;
    int t = idx >> 3, j = idx & 7;
    float2 x = qsv_l[j * TT + t];
    x.y = sv_l[__float_as_int(x.y)];
    qsv_l[j * TT + t] = x;
  }
  __syncthreads();   // (3) qsv final; Eq staging dead -> big becomes pacc

  // ---- scan: barrier-free. rvec in-register; P[t2][m] -> pacc[m*PSTR+t2] ----
  float rvec = 0.f;
  const float2* qsv_g = qsv_l + g * TT;
  float* pacc = big + g * (MM * PSTR);

  for (int c = 0; c < NCH; ++c) {
    const float4* x4 = (const float4*)(qsv_g + c * CH);   // 2 steps per b128
    #pragma unroll
    for (int h = 0; h < CH / 2; ++h) {
      float4 x = x4[h];
      int q0 = __float_as_int(x.x);
      float av0 = att_l[q0 * MM + m];       // bank m, 2-way across groups = free
      float p0 = av0 * rvec;
      rvec = fmaf(av0, x.y, rvec);          // loop-carried dep #1
      int q1 = __float_as_int(x.z);
      float av1 = att_l[q1 * MM + m];
      float p1 = av1 * rvec;
      rvec = fmaf(av1, x.w, rvec);          // loop-carried dep #2
      *(float2*)(pacc + m * PSTR + 2 * h) = make_float2(p0, p1);  // b64, ~2-way
    }
    // reduce: lane j=m sums step-row t2=m over the 32 slots (banks (2k+m)%32)
    float s = 0.f;
    #pragma unroll
    for (int k = 0; k < MM; ++k) s += pacc[k * PSTR + m];
    int t = c * CH + m;
    int q = __float_as_int(qsv_g[t].x);
    pred_l[t * 9 + g] = s + sq_l[q];
  }

  __syncthreads();   // (4) pred_l complete

  // ---- coalesced store: 16B per thread ----
  {
    int t = tid >> 1, h = tid & 1;
    float4 v;
    v.x = pred_l[t * 9 + h * 4 + 0];
    v.y = pred_l[t * 9 + h * 4 + 1];
    v.z = pred_l[t * 9 + h * 4 + 2];
    v.w = pred_l[t * 9 + h * 4 + 3];
    *(float4*)(out + t * BB + b0 + h * 4) = v;
  }
}

extern "C" void kernel_launch(void* const* d_in, const int* in_sizes, int n_in,
                              void* d_out, int out_size, void* d_ws, size_t ws_size,
                              hipStream_t stream) {
  const int*   questions = (const int*)d_in[0];
  const int*   answers   = (const int*)d_in[1];
  const float* Eq = (const float*)d_in[2];
  const float* Ev = (const float*)d_in[3];
  const float* Wa = (const float*)d_in[4];
  const float* ba = (const float*)d_in[5];
  const float* Wf = (const float*)d_in[6];
  const float* bf = (const float*)d_in[7];
  float* out = (float*)d_out;

  hipLaunchKernelGGL(dkvmn_fused, dim3(BB / BPB), dim3(NTHR), 0, stream,
                     questions, answers, Eq, Ev, Wa, ba, Wf, bf, out);
}

// Round 5
// 17.014 us; speedup vs baseline: 2.5723x; 1.1818x over previous
//
#include <hip/hip_runtime.h>
#include <math.h>

#define VOCAB 100
#define TT    128
#define BB    1024
#define MM    32
#define DQ    64
#define DV    64
#define BPB   8                 // batches per block (one 32-lane group each)
#define NTHR  256               // 8 groups x 32 lanes = 4 waves
#define CH    32                // t-chunk
#define NCH   (TT / CH)
#define ASTR  36                // att_l row stride: 16B-aligned, banks (4q+m)%32
#define PSTR  36                // pacc row stride [t2][m]

// Single fused kernel. Table build: phase B writes raw logits (no cross-lane
// ops), phase C does a transposed register softmax (lane = q, zero shuffles),
// concurrent with phase D (sq/sv) on the other waves. Scan is barrier-free
// (group-private pacc, writer==reader wave); preds stored direct to global.
__global__ __launch_bounds__(NTHR) void dkvmn_fused(
    const int* __restrict__ questions,
    const int* __restrict__ answers,
    const float* __restrict__ Eq,
    const float* __restrict__ Ev,
    const float* __restrict__ Wa,
    const float* __restrict__ ba,
    const float* __restrict__ Wf,
    const float* __restrict__ bf,
    float* __restrict__ out) {

  __shared__ __align__(16) float att_l[VOCAB * ASTR];   // logits, then att
  __shared__ float sq_l[VOCAB];
  __shared__ float sv_l[VOCAB];
  __shared__ __align__(16) float wf_l[2 * DQ + 1];      // Wf_q | Wf_r | bf
  __shared__ __align__(16) float2 qsv_l[BPB * TT];      // {q bits, w -> sval}
  __shared__ __align__(16) float big[BPB * CH * PSTR];  // pacc 9216f; Eq stage 6400f

  const int tid = threadIdx.x;
  const int b0  = blockIdx.x * BPB;
  const int g   = tid >> 5;     // local batch / group
  const int m   = tid & 31;     // memory slot

  // ---- stage Eq -> big ----
  {
    const float4* Eq4 = (const float4*)Eq;
    float4* dst = (float4*)big;
    #pragma unroll
    for (int it = 0; it < 7; ++it) {
      int i = tid + it * NTHR;
      if (i < VOCAB * DQ / 4) dst[i] = Eq4[i];
    }
  }
  if (tid < 2 * DQ) wf_l[tid] = Wf[tid];
  if (tid == NTHR - 1) wf_l[2 * DQ] = bf[0];

  // ---- q/a -> {q, write-index} (w -> sval later) ----
  #pragma unroll
  for (int it = 0; it < 4; ++it) {
    int idx = tid + it * NTHR;          // < 1024 = TT*BPB
    int t = idx >> 3, j = idx & 7;
    int gi = t * BB + b0 + j;
    int q = questions[gi];
    int a = answers[gi];
    int w = (q * 2 + a) % VOCAB;
    qsv_l[j * TT + t] = make_float2(__int_as_float(q), __int_as_float(w));
  }

  // ---- Wa column for slot m -> registers ----
  float wa[DQ];
  #pragma unroll
  for (int k = 0; k < DQ; ++k) wa[k] = Wa[k * MM + m];
  const float bam = ba[m];

  __syncthreads();   // (1) staging done

  // ---- phase B: raw logits. Odd waves read Eq via global/L1, even via LDS
  //      (two pipes in parallel). No shuffles, no exp here. ----
  if ((tid >> 6) & 1) {
    for (int q = g; q < VOCAB; q += BPB) {
      const float4* eq4 = (const float4*)(Eq + q * DQ);
      float ax = 0.f, ay = 0.f, az = 0.f, aw = 0.f;
      #pragma unroll
      for (int k4 = 0; k4 < DQ / 4; ++k4) {
        float4 e = eq4[k4];
        ax = fmaf(e.x, wa[4 * k4 + 0], ax);
        ay = fmaf(e.y, wa[4 * k4 + 1], ay);
        az = fmaf(e.z, wa[4 * k4 + 2], az);
        aw = fmaf(e.w, wa[4 * k4 + 3], aw);
      }
      att_l[q * ASTR + m] = (ax + ay) + (az + aw) + bam;
    }
  } else {
    for (int q = g; q < VOCAB; q += BPB) {
      const float4* eq4 = (const float4*)(big + q * DQ);
      float ax = 0.f, ay = 0.f, az = 0.f, aw = 0.f;
      #pragma unroll
      for (int k4 = 0; k4 < DQ / 4; ++k4) {
        float4 e = eq4[k4];
        ax = fmaf(e.x, wa[4 * k4 + 0], ax);
        ay = fmaf(e.y, wa[4 * k4 + 1], ay);
        az = fmaf(e.z, wa[4 * k4 + 2], az);
        aw = fmaf(e.w, wa[4 * k4 + 3], aw);
      }
      att_l[q * ASTR + m] = (ax + ay) + (az + aw) + bam;
    }
  }

  __syncthreads();   // (2) logits ready

  // ---- phase C (waves 0-1): transposed softmax, lane = q, all-register.
  //      phase D (waves 2-3): sq/sv tables. Concurrent. ----
  if (tid < 128) {
    if (tid < VOCAB) {
      const int q = tid;
      float4* row = (float4*)(att_l + q * ASTR);
      float v[MM];
      #pragma unroll
      for (int j = 0; j < 8; ++j) {
        float4 x = row[j];
        v[4 * j + 0] = x.x; v[4 * j + 1] = x.y;
        v[4 * j + 2] = x.z; v[4 * j + 3] = x.w;
      }
      float mx = v[0];
      #pragma unroll
      for (int k = 1; k < MM; ++k) mx = fmaxf(mx, v[k]);
      float sm = 0.f;
      #pragma unroll
      for (int k = 0; k < MM; ++k) { v[k] = __expf(v[k] - mx); sm += v[k]; }
      const float inv = __builtin_amdgcn_rcpf(sm);
      #pragma unroll
      for (int j = 0; j < 8; ++j)
        row[j] = make_float4(v[4 * j + 0] * inv, v[4 * j + 1] * inv,
                             v[4 * j + 2] * inv, v[4 * j + 3] * inv);
    }
  } else if (tid - 128 < VOCAB) {
    const int v = tid - 128;
    const float4* eq4 = (const float4*)(big + v * DQ);
    const float4* wfq = (const float4*)wf_l;
    float s = 0.f;
    #pragma unroll
    for (int k4 = 0; k4 < DQ / 4; ++k4) {
      float4 e = eq4[k4], w = wfq[k4];
      s = fmaf(e.x, w.x, fmaf(e.y, w.y, fmaf(e.z, w.z, fmaf(e.w, w.w, s))));
    }
    sq_l[v] = s + wf_l[2 * DQ];
    const float4* ev4 = (const float4*)Ev + v * (DV / 4);
    const float4* wfr = (const float4*)(wf_l + DQ);
    float s2 = 0.f;
    #pragma unroll
    for (int k4 = 0; k4 < DV / 4; ++k4) {
      float4 e = ev4[k4], w = wfr[k4];
      s2 = fmaf(e.x, w.x, fmaf(e.y, w.y, fmaf(e.z, w.z, fmaf(e.w, w.w, s2))));
    }
    sv_l[v] = s2;
  }

  __syncthreads();   // (3) att/sq/sv ready

  // ---- convert stored w -> sval ----
  #pragma unroll
  for (int it = 0; it < 4; ++it) {
    int idx = tid + it * NTHR;
    int t = idx >> 3, j = idx & 7;
    float2 x = qsv_l[j * TT + t];
    x.y = sv_l[__float_as_int(x.y)];
    qsv_l[j * TT + t] = x;
  }
  __syncthreads();   // (4) qsv final; Eq staging dead -> big becomes pacc

  // ---- scan: barrier-free. pacc layout [t2][m]; reduce = 8x b128/lane. ----
  float rvec = 0.f;
  const float2* qsv_g = qsv_l + g * TT;
  float* pacc = big + g * (CH * PSTR);

  for (int c = 0; c < NCH; ++c) {
    const float4* x4 = (const float4*)(qsv_g + c * CH);   // 2 steps per b128
    #pragma unroll
    for (int h = 0; h < CH / 2; ++h) {
      float4 x = x4[h];
      int q0 = __float_as_int(x.x);
      float av0 = att_l[q0 * ASTR + m];          // banks (4q+m): conflict-free
      pacc[(2 * h + 0) * PSTR + m] = av0 * rvec; // banks (4t2+m): conflict-free
      rvec = fmaf(av0, x.y, rvec);               // loop-carried dep #1
      int q1 = __float_as_int(x.z);
      float av1 = att_l[q1 * ASTR + m];
      pacc[(2 * h + 1) * PSTR + m] = av1 * rvec;
      rvec = fmaf(av1, x.w, rvec);               // loop-carried dep #2
    }
    // reduce: lane m owns step t2 = m; row read as 8x b128 (2-way max = free)
    const float4* prow = (const float4*)(pacc + m * PSTR);
    float s = 0.f;
    #pragma unroll
    for (int j = 0; j < 8; ++j) {
      float4 r = prow[j];
      s += (r.x + r.y) + (r.z + r.w);
    }
    int t = c * CH + m;
    int q = __float_as_int(qsv_g[t].x);
    // direct store: the block's 8 columns of row t form one 32B sector
    out[t * BB + b0 + g] = s + sq_l[q];
  }
}

extern "C" void kernel_launch(void* const* d_in, const int* in_sizes, int n_in,
                              void* d_out, int out_size, void* d_ws, size_t ws_size,
                              hipStream_t stream) {
  const int*   questions = (const int*)d_in[0];
  const int*   answers   = (const int*)d_in[1];
  const float* Eq = (const float*)d_in[2];
  const float* Ev = (const float*)d_in[3];
  const float* Wa = (const float*)d_in[4];
  const float* ba = (const float*)d_in[5];
  const float* Wf = (const float*)d_in[6];
  const float* bf = (const float*)d_in[7];
  float* out = (float*)d_out;

  hipLaunchKernelGGL(dkvmn_fused, dim3(BB / BPB), dim3(NTHR), 0, stream,
                     questions, answers, Eq, Ev, Wa, ba, Wf, bf, out);
}